// Round 2
// baseline (2761.771 us; speedup 1.0000x reference)
//
#include <hip/hip_runtime.h>

typedef unsigned short u16;
typedef unsigned int u32;
typedef __attribute__((ext_vector_type(8))) short short8;
typedef __attribute__((ext_vector_type(4))) float float4_t;

__device__ __forceinline__ float bf2f(u16 v) {
    union { u32 u; float f; } x; x.u = ((u32)v) << 16; return x.f;
}
__device__ __forceinline__ u16 f2bf(float f) {
    union { float f; u32 u; } x; x.f = f;
    u32 r = x.u + 0x7FFFu + ((x.u >> 16) & 1u);
    return (u16)(r >> 16);
}
__device__ __forceinline__ float sigm(float x) { return 1.f / (1.f + __expf(-x)); }
__device__ __forceinline__ float tanh_(float x) { return 1.f - 2.f / (1.f + __expf(2.f * x)); }

__device__ __forceinline__ float4_t mfma16(short8 a, short8 b, float4_t c) {
    return __builtin_amdgcn_mfma_f32_16x16x32_bf16(a, b, c, 0, 0, 0);
}

// fragment loaders: 8 contiguous K-elements starting at p
__device__ __forceinline__ short8 ldfrag(const u16* p) { return *(const short8*)p; }
__device__ __forceinline__ short8 ldfrag(const float* p) {
    float4_t a = *(const float4_t*)p;
    float4_t b = *(const float4_t*)(p + 4);
    short8 r;
#pragma unroll
    for (int j = 0; j < 4; ++j) { r[j] = (short)f2bf(a[j]); r[4 + j] = (short)f2bf(b[j]); }
    return r;
}

// ---------------------------------------------------------------------------
// gemm_ih: Xih[M,512](bf16) = A[M,128] @ W[512,128]^T + b1 + b2
// Block 256 thr; tile [64 rows, 128 cols]; grid (nblk, 4).
// ---------------------------------------------------------------------------
template<typename AT>
__global__ __launch_bounds__(256) void gemm_ih(
    const AT* __restrict__ A, const float* __restrict__ W,
    const float* __restrict__ b1, const float* __restrict__ b2,
    u16* __restrict__ C, int M)
{
    const int P = 512;
    const int lane = threadIdx.x & 63;
    const int w    = threadIdx.x >> 6;
    const int l15  = lane & 15;
    const int quad = lane >> 4;
    const int rowbase = blockIdx.x * 64;
    const int colbase = blockIdx.y * 128 + w * 32;

    short8 af[4][4];
#pragma unroll
    for (int mb = 0; mb < 4; ++mb) {
        int row = rowbase + mb * 16 + l15;
        if (row >= M) row = M - 1;
        const AT* ap = A + (size_t)row * 128 + quad * 8;
#pragma unroll
        for (int kb = 0; kb < 4; ++kb) af[mb][kb] = ldfrag(ap + kb * 32);
    }
    short8 bfr[2][4];
#pragma unroll
    for (int nb = 0; nb < 2; ++nb) {
        int col = colbase + nb * 16 + l15;
        const float* wp = W + (size_t)col * 128 + quad * 8;
#pragma unroll
        for (int kb = 0; kb < 4; ++kb) bfr[nb][kb] = ldfrag(wp + kb * 32);
    }
    const float4_t z4 = {0.f, 0.f, 0.f, 0.f};
    float bias[2];
#pragma unroll
    for (int nb = 0; nb < 2; ++nb) {
        int col = colbase + nb * 16 + l15;
        bias[nb] = b1[col] + b2[col];
    }
#pragma unroll
    for (int mb = 0; mb < 4; ++mb)
#pragma unroll
        for (int nb = 0; nb < 2; ++nb) {
            float4_t a = z4;
#pragma unroll
            for (int kb = 0; kb < 4; ++kb) a = mfma16(af[mb][kb], bfr[nb][kb], a);
#pragma unroll
            for (int r = 0; r < 4; ++r) {
                int row = rowbase + mb * 16 + quad * 4 + r;
                int col = colbase + nb * 16 + l15;
                if (row < M) C[(size_t)row * P + col] = f2bf(a[r] + bias[nb]);
            }
        }
}

// ---------------------------------------------------------------------------
// gemm_out: P[M,128](f32) = A1@W1^T + A2@W2^T + bias ; per-col sum/sumsq atomics
// ---------------------------------------------------------------------------
template<typename T>
__device__ __forceinline__ void accum_gemm(
    const T* __restrict__ A, const float* __restrict__ W,
    float4_t (&acc)[4][2], int M, int rowbase, int colbase, int l15, int quad)
{
    short8 af[4][4];
#pragma unroll
    for (int mb = 0; mb < 4; ++mb) {
        int row = rowbase + mb * 16 + l15;
        if (row >= M) row = M - 1;
        const T* ap = A + (size_t)row * 128 + quad * 8;
#pragma unroll
        for (int kb = 0; kb < 4; ++kb) af[mb][kb] = ldfrag(ap + kb * 32);
    }
    short8 bfr[2][4];
#pragma unroll
    for (int nb = 0; nb < 2; ++nb) {
        int col = colbase + nb * 16 + l15;
        const float* wp = W + (size_t)col * 128 + quad * 8;
#pragma unroll
        for (int kb = 0; kb < 4; ++kb) bfr[nb][kb] = ldfrag(wp + kb * 32);
    }
#pragma unroll
    for (int mb = 0; mb < 4; ++mb)
#pragma unroll
        for (int nb = 0; nb < 2; ++nb)
#pragma unroll
            for (int kb = 0; kb < 4; ++kb)
                acc[mb][nb] = mfma16(af[mb][kb], bfr[nb][kb], acc[mb][nb]);
}

template<typename AT2>
__global__ __launch_bounds__(256) void gemm_out(
    const u16* __restrict__ A1, const float* __restrict__ W1,
    const AT2* __restrict__ A2, const float* __restrict__ W2,
    const float* __restrict__ bias, float* __restrict__ C,
    float* __restrict__ stats, int M)
{
    const int P = 128;
    const int lane = threadIdx.x & 63;
    const int w    = threadIdx.x >> 6;
    const int l15  = lane & 15;
    const int quad = lane >> 4;
    const int rowbase = blockIdx.x * 64;
    const int colbase = w * 32;

    float4_t acc[4][2];
    const float4_t z4 = {0.f, 0.f, 0.f, 0.f};
#pragma unroll
    for (int mb = 0; mb < 4; ++mb)
#pragma unroll
        for (int nb = 0; nb < 2; ++nb) acc[mb][nb] = z4;

    accum_gemm(A1, W1, acc, M, rowbase, colbase, l15, quad);
    accum_gemm(A2, W2, acc, M, rowbase, colbase, l15, quad);

    float s[2] = {0.f, 0.f}, sq[2] = {0.f, 0.f};
#pragma unroll
    for (int nb = 0; nb < 2; ++nb) {
        int col = colbase + nb * 16 + l15;
        float bb = bias[col];
#pragma unroll
        for (int mb = 0; mb < 4; ++mb)
#pragma unroll
            for (int r = 0; r < 4; ++r) {
                int row = rowbase + mb * 16 + quad * 4 + r;
                if (row < M) {
                    float v = acc[mb][nb][r] + bb;
                    C[(size_t)row * P + col] = v;
                    s[nb] += v; sq[nb] += v * v;
                }
            }
    }
#pragma unroll
    for (int nb = 0; nb < 2; ++nb) {
        float t1 = s[nb], t2 = sq[nb];
        t1 += __shfl_xor(t1, 16); t1 += __shfl_xor(t1, 32);
        t2 += __shfl_xor(t2, 16); t2 += __shfl_xor(t2, 32);
        int col = colbase + nb * 16 + l15;
        if (quad == 0) atomicAdd(&stats[col], t1);
        if (quad == 1) atomicAdd(&stats[P + col], t2);
    }
}

// ---------------------------------------------------------------------------
// Persistent LSTM aggregator. 512 thr (8 waves), 64 nodes/block, 16 steps.
// ---------------------------------------------------------------------------
__global__ __launch_bounds__(512) void lstm_kernel(
    const u16* __restrict__ Xih,   // [N,512] bf16
    const int* __restrict__ nbr,   // [N,16]
    const float* __restrict__ Whh, // [512,128] f32
    u16* __restrict__ Hout,        // [N,128] bf16
    int N)
{
    __shared__ u16 hbuf[64][136];
    __shared__ int nbrs[64][16];
    const int tid  = threadIdx.x;
    const int lane = tid & 63;
    const int w    = tid >> 6;           // wave 0..7
    const int l15  = lane & 15;
    const int quad = lane >> 4;
    const int base = blockIdx.x * 64;

    short8 whB[4][4];
#pragma unroll
    for (int g = 0; g < 4; ++g) {
        int col = 128 * g + 16 * w + l15;
        const float* wp = Whh + (size_t)col * 128 + quad * 8;
#pragma unroll
        for (int kb = 0; kb < 4; ++kb) whB[g][kb] = ldfrag(wp + kb * 32);
    }
    // identity B-frag: B[k][n] = (k == n + 16*(w&1))
    short8 I;
    {
        int off = (w & 1) ? 16 : 0;
#pragma unroll
        for (int j = 0; j < 8; ++j) {
            int k = quad * 8 + j;
            I[j] = (short)((k == l15 + off) ? 0x3F80 : 0);
        }
    }
    u32* hz = (u32*)&hbuf[0][0];
    for (int i = tid; i < 64 * 136 / 2; i += 512) hz[i] = 0u;
    for (int i = tid; i < 64 * 16; i += 512) {
        int node = base + (i >> 4);
        if (node >= N) node = N - 1;
        nbrs[i >> 4][i & 15] = nbr[(size_t)node * 16 + (i & 15)];
    }

    const float4_t z4 = {0.f, 0.f, 0.f, 0.f};
    float4_t c[4];
#pragma unroll
    for (int mb = 0; mb < 4; ++mb) c[mb] = z4;
    float4_t hlast[4];
    const int xcol0 = 32 * (w >> 1);

    for (int t = 0; t < 16; ++t) {
        __syncthreads();               // h(t-1) writes visible
        float4_t z[4][4];
#pragma unroll
        for (int mb = 0; mb < 4; ++mb) {
            int m = mb * 16 + l15;
            int nb_ = nbrs[m][t];
            const u16* xp = Xih + (size_t)nb_ * 512 + xcol0 + quad * 8;
            short8 xf[4];
#pragma unroll
            for (int g = 0; g < 4; ++g) xf[g] = *(const short8*)(xp + 128 * g);
            short8 ha[4];
            const u16* hp = &hbuf[m][quad * 8];
#pragma unroll
            for (int kb = 0; kb < 4; ++kb) ha[kb] = *(const short8*)(hp + kb * 32);
#pragma unroll
            for (int g = 0; g < 4; ++g) {
                float4_t a = mfma16(ha[0], whB[g][0], z4);
                a = mfma16(ha[1], whB[g][1], a);
                a = mfma16(ha[2], whB[g][2], a);
                a = mfma16(ha[3], whB[g][3], a);
                a = mfma16(xf[g], I, a);   // += X_ih[nbr, gate g cols]
                z[mb][g] = a;
            }
        }
        __syncthreads();               // all reads done before overwrite
#pragma unroll
        for (int mb = 0; mb < 4; ++mb) {
#pragma unroll
            for (int r = 0; r < 4; ++r) {
                float i_ = sigm(z[mb][0][r]);
                float f_ = sigm(z[mb][1][r]);
                float g_ = tanh_(z[mb][2][r]);
                float o_ = sigm(z[mb][3][r]);
                float cc = f_ * c[mb][r] + i_ * g_;
                c[mb][r] = cc;
                float hh = o_ * tanh_(cc);
                hlast[mb][r] = hh;
                hbuf[mb * 16 + quad * 4 + r][16 * w + l15] = f2bf(hh);
            }
        }
    }
#pragma unroll
    for (int mb = 0; mb < 4; ++mb)
#pragma unroll
        for (int r = 0; r < 4; ++r) {
            int row = base + mb * 16 + quad * 4 + r;
            if (row < N) Hout[(size_t)row * 128 + 16 * w + l15] = f2bf(hlast[mb][r]);
        }
}

// ---------------------------------------------------------------------------
__global__ void zero_stats(float* s) { s[threadIdx.x] = 0.f; }   // 256 thr

__global__ void bn_prep(float* stats, const float* __restrict__ gamma,
                        const float* __restrict__ beta, float invN)
{
    int cidx = threadIdx.x;   // 0..127
    float s = stats[cidx], sq = stats[128 + cidx];
    float mu = s * invN;
    float var = sq * invN - mu * mu;
    float sc = gamma[cidx] * rsqrtf(var + 1e-5f);
    stats[256 + cidx] = sc;
    stats[384 + cidx] = beta[cidx] - mu * sc;
}

template<typename OT>
__global__ __launch_bounds__(256) void bn_apply(
    const float* __restrict__ X, const float* __restrict__ stats,
    OT* __restrict__ Y, int M, int relu)
{
    int gid = blockIdx.x * 256 + threadIdx.x;
    int row = gid >> 4;
    int cs  = (gid & 15) * 8;
    if (row >= M) return;
    float4_t a = *(const float4_t*)(X + (size_t)row * 128 + cs);
    float4_t b = *(const float4_t*)(X + (size_t)row * 128 + cs + 4);
    float v[8];
#pragma unroll
    for (int j = 0; j < 8; ++j) {
        float x = (j < 4) ? a[j] : b[j - 4];
        float t = x * stats[256 + cs + j] + stats[384 + cs + j];
        v[j] = relu ? fmaxf(t, 0.f) : t;
    }
    if constexpr (sizeof(OT) == 2) {
        short8 ov;
#pragma unroll
        for (int j = 0; j < 8; ++j) ov[j] = (short)f2bf(v[j]);
        *(short8*)((u16*)Y + (size_t)row * 128 + cs) = ov;
    } else {
        float4_t o1, o2;
#pragma unroll
        for (int j = 0; j < 4; ++j) { o1[j] = v[j]; o2[j] = v[4 + j]; }
        *(float4_t*)((float*)Y + (size_t)row * 128 + cs) = o1;
        *(float4_t*)((float*)Y + (size_t)row * 128 + cs + 4) = o2;
    }
}

// ---------------------------------------------------------------------------
extern "C" void kernel_launch(void* const* d_in, const int* in_sizes, int n_in,
                              void* d_out, int out_size, void* d_ws, size_t ws_size,
                              hipStream_t stream)
{
    const float* in_feat = (const float*)d_in[0];
    const int*   nbr     = (const int*)d_in[1];
    const float* Wih1 = (const float*)d_in[2];
    const float* Whh1 = (const float*)d_in[3];
    const float* bih1 = (const float*)d_in[4];
    const float* bhh1 = (const float*)d_in[5];
    const float* Wself1  = (const float*)d_in[6];
    const float* bself1  = (const float*)d_in[7];
    const float* Wneigh1 = (const float*)d_in[8];
    const float* gamma1  = (const float*)d_in[9];
    const float* beta1   = (const float*)d_in[10];
    const float* Wih2 = (const float*)d_in[11];
    const float* Whh2 = (const float*)d_in[12];
    const float* bih2 = (const float*)d_in[13];
    const float* bhh2 = (const float*)d_in[14];
    const float* Wself2  = (const float*)d_in[15];
    const float* bself2  = (const float*)d_in[16];
    const float* Wneigh2 = (const float*)d_in[17];
    const float* gamma2  = (const float*)d_in[18];
    const float* beta2   = (const float*)d_in[19];

    const int N = in_sizes[0] / 128;

    char* ws = (char*)d_ws;
    // region0: Xih (N*512 bf16 = N*1024 B) alternating with P (N*128 f32 = N*512 B)
    u16*   Xih   = (u16*)ws;
    float* Pbuf  = (float*)ws;
    u16*   hn    = (u16*)(ws + (size_t)N * 1024);
    float* stats = (float*)(ws + (size_t)N * 1024 + (size_t)N * 256);
    u16*   hcur  = (u16*)d_out;          // bf16 scratch inside d_out (dead before final write)

    const int nblk = (N + 63) / 64;
    const float invN = 1.0f / (float)N;
    const int bnblk = (N * 16 + 255) / 256;

    // ---------------- layer 1 ----------------
    zero_stats<<<dim3(1), dim3(256), 0, stream>>>(stats);
    gemm_ih<float><<<dim3(nblk, 4), dim3(256), 0, stream>>>(in_feat, Wih1, bih1, bhh1, Xih, N);
    lstm_kernel<<<dim3(nblk), dim3(512), 0, stream>>>(Xih, nbr, Whh1, hn, N);
    gemm_out<float><<<dim3(nblk, 1), dim3(256), 0, stream>>>(hn, Wneigh1, in_feat, Wself1,
                                                             bself1, Pbuf, stats, N);
    bn_prep<<<dim3(1), dim3(128), 0, stream>>>(stats, gamma1, beta1, invN);
    bn_apply<u16><<<dim3(bnblk), dim3(256), 0, stream>>>(Pbuf, stats, hcur, N, 1);

    // ---------------- layer 2 ----------------
    zero_stats<<<dim3(1), dim3(256), 0, stream>>>(stats);
    gemm_ih<u16><<<dim3(nblk, 4), dim3(256), 0, stream>>>(hcur, Wih2, bih2, bhh2, Xih, N);
    lstm_kernel<<<dim3(nblk), dim3(512), 0, stream>>>(Xih, nbr, Whh2, hn, N);
    gemm_out<u16><<<dim3(nblk, 1), dim3(256), 0, stream>>>(hn, Wneigh2, hcur, Wself2,
                                                           bself2, Pbuf, stats, N);
    bn_prep<<<dim3(1), dim3(128), 0, stream>>>(stats, gamma2, beta2, invN);
    bn_apply<float><<<dim3(bnblk), dim3(256), 0, stream>>>(Pbuf, stats, (float*)d_out, N, 0);
}

// Round 3
// 1682.646 us; speedup vs baseline: 1.6413x; 1.6413x over previous
//
#include <hip/hip_runtime.h>

typedef unsigned short u16;
typedef unsigned int u32;
typedef unsigned long long u64;
typedef __attribute__((ext_vector_type(8))) short short8;
typedef __attribute__((ext_vector_type(4))) float float4_t;

__device__ __forceinline__ float bf2f(u16 v) {
    union { u32 u; float f; } x; x.u = ((u32)v) << 16; return x.f;
}
__device__ __forceinline__ u16 f2bf(float f) {
    union { float f; u32 u; } x; x.f = f;
    u32 r = x.u + 0x7FFFu + ((x.u >> 16) & 1u);
    return (u16)(r >> 16);
}
// pack two floats' (biased-rounded) bf16 into one u32: [hi:lo]
__device__ __forceinline__ u32 pk2bf(float hi, float lo) {
    union { float f; u32 u; } a, b; a.f = hi; b.f = lo;
    return __builtin_amdgcn_perm(a.u + 0x8000u, b.u + 0x8000u, 0x07060302u);
}
#define LOG2E 1.44269504088896340736f
__device__ __forceinline__ float sigm(float x) {   // 1/(1+e^-x): mul,exp,add,rcp
    return __builtin_amdgcn_rcpf(1.f + __builtin_amdgcn_exp2f(-LOG2E * x));
}
__device__ __forceinline__ float tanh_(float x) {  // 1 - 2/(1+e^{2x})
    float t = __builtin_amdgcn_exp2f(2.f * LOG2E * x);
    return 1.f - 2.f * __builtin_amdgcn_rcpf(1.f + t);
}

__device__ __forceinline__ float4_t mfma16(short8 a, short8 b, float4_t c) {
    return __builtin_amdgcn_mfma_f32_16x16x32_bf16(a, b, c, 0, 0, 0);
}

// fragment loaders: 8 contiguous K-elements starting at p
__device__ __forceinline__ short8 ldfrag(const u16* p) { return *(const short8*)p; }
__device__ __forceinline__ short8 ldfrag(const float* p) {
    float4_t a = *(const float4_t*)p;
    float4_t b = *(const float4_t*)(p + 4);
    short8 r;
#pragma unroll
    for (int j = 0; j < 4; ++j) { r[j] = (short)f2bf(a[j]); r[4 + j] = (short)f2bf(b[j]); }
    return r;
}

// ---------------------------------------------------------------------------
// gemm_ih: Xih[M,512](bf16) = A[M,128] @ W[512,128]^T + b1 + b2
// ---------------------------------------------------------------------------
template<typename AT>
__global__ __launch_bounds__(256) void gemm_ih(
    const AT* __restrict__ A, const float* __restrict__ W,
    const float* __restrict__ b1, const float* __restrict__ b2,
    u16* __restrict__ C, int M)
{
    const int P = 512;
    const int lane = threadIdx.x & 63;
    const int w    = threadIdx.x >> 6;
    const int l15  = lane & 15;
    const int quad = lane >> 4;
    const int rowbase = blockIdx.x * 64;
    const int colbase = blockIdx.y * 128 + w * 32;

    short8 af[4][4];
#pragma unroll
    for (int mb = 0; mb < 4; ++mb) {
        int row = rowbase + mb * 16 + l15;
        if (row >= M) row = M - 1;
        const AT* ap = A + (size_t)row * 128 + quad * 8;
#pragma unroll
        for (int kb = 0; kb < 4; ++kb) af[mb][kb] = ldfrag(ap + kb * 32);
    }
    short8 bfr[2][4];
#pragma unroll
    for (int nb = 0; nb < 2; ++nb) {
        int col = colbase + nb * 16 + l15;
        const float* wp = W + (size_t)col * 128 + quad * 8;
#pragma unroll
        for (int kb = 0; kb < 4; ++kb) bfr[nb][kb] = ldfrag(wp + kb * 32);
    }
    const float4_t z4 = {0.f, 0.f, 0.f, 0.f};
    float bias[2];
#pragma unroll
    for (int nb = 0; nb < 2; ++nb) {
        int col = colbase + nb * 16 + l15;
        bias[nb] = b1[col] + b2[col];
    }
#pragma unroll
    for (int mb = 0; mb < 4; ++mb)
#pragma unroll
        for (int nb = 0; nb < 2; ++nb) {
            float4_t a = z4;
#pragma unroll
            for (int kb = 0; kb < 4; ++kb) a = mfma16(af[mb][kb], bfr[nb][kb], a);
#pragma unroll
            for (int r = 0; r < 4; ++r) {
                int row = rowbase + mb * 16 + quad * 4 + r;
                int col = colbase + nb * 16 + l15;
                if (row < M) C[(size_t)row * P + col] = f2bf(a[r] + bias[nb]);
            }
        }
}

// ---------------------------------------------------------------------------
// gemm_out: P[M,128](f32) = A1@W1^T + A2@W2^T + bias ; per-col sum/sumsq atomics
// ---------------------------------------------------------------------------
template<typename T>
__device__ __forceinline__ void accum_gemm(
    const T* __restrict__ A, const float* __restrict__ W,
    float4_t (&acc)[4][2], int M, int rowbase, int colbase, int l15, int quad)
{
    short8 af[4][4];
#pragma unroll
    for (int mb = 0; mb < 4; ++mb) {
        int row = rowbase + mb * 16 + l15;
        if (row >= M) row = M - 1;
        const T* ap = A + (size_t)row * 128 + quad * 8;
#pragma unroll
        for (int kb = 0; kb < 4; ++kb) af[mb][kb] = ldfrag(ap + kb * 32);
    }
    short8 bfr[2][4];
#pragma unroll
    for (int nb = 0; nb < 2; ++nb) {
        int col = colbase + nb * 16 + l15;
        const float* wp = W + (size_t)col * 128 + quad * 8;
#pragma unroll
        for (int kb = 0; kb < 4; ++kb) bfr[nb][kb] = ldfrag(wp + kb * 32);
    }
#pragma unroll
    for (int mb = 0; mb < 4; ++mb)
#pragma unroll
        for (int nb = 0; nb < 2; ++nb)
#pragma unroll
            for (int kb = 0; kb < 4; ++kb)
                acc[mb][nb] = mfma16(af[mb][kb], bfr[nb][kb], acc[mb][nb]);
}

template<typename AT2>
__global__ __launch_bounds__(256) void gemm_out(
    const u16* __restrict__ A1, const float* __restrict__ W1,
    const AT2* __restrict__ A2, const float* __restrict__ W2,
    const float* __restrict__ bias, float* __restrict__ C,
    float* __restrict__ stats, int M)
{
    const int P = 128;
    const int lane = threadIdx.x & 63;
    const int w    = threadIdx.x >> 6;
    const int l15  = lane & 15;
    const int quad = lane >> 4;
    const int rowbase = blockIdx.x * 64;
    const int colbase = w * 32;

    float4_t acc[4][2];
    const float4_t z4 = {0.f, 0.f, 0.f, 0.f};
#pragma unroll
    for (int mb = 0; mb < 4; ++mb)
#pragma unroll
        for (int nb = 0; nb < 2; ++nb) acc[mb][nb] = z4;

    accum_gemm(A1, W1, acc, M, rowbase, colbase, l15, quad);
    accum_gemm(A2, W2, acc, M, rowbase, colbase, l15, quad);

    float s[2] = {0.f, 0.f}, sq[2] = {0.f, 0.f};
#pragma unroll
    for (int nb = 0; nb < 2; ++nb) {
        int col = colbase + nb * 16 + l15;
        float bb = bias[col];
#pragma unroll
        for (int mb = 0; mb < 4; ++mb)
#pragma unroll
            for (int r = 0; r < 4; ++r) {
                int row = rowbase + mb * 16 + quad * 4 + r;
                if (row < M) {
                    float v = acc[mb][nb][r] + bb;
                    C[(size_t)row * P + col] = v;
                    s[nb] += v; sq[nb] += v * v;
                }
            }
    }
#pragma unroll
    for (int nb = 0; nb < 2; ++nb) {
        float t1 = s[nb], t2 = sq[nb];
        t1 += __shfl_xor(t1, 16); t1 += __shfl_xor(t1, 32);
        t2 += __shfl_xor(t2, 16); t2 += __shfl_xor(t2, 32);
        int col = colbase + nb * 16 + l15;
        if (quad == 0) atomicAdd(&stats[col], t1);
        if (quad == 1) atomicAdd(&stats[P + col], t2);
    }
}

// ---------------------------------------------------------------------------
// Persistent LSTM aggregator, transposed formulation: z^T = Whh*h^T + I*Xih^T.
// 512 thr (8 waves), 64 nodes/block, 16 steps. Wave w owns dim-slice
// [16w,16w+16) of each gate. C-layout: lane holds dims quad*4+r of node l15.
// Single barrier/step (double-buffered hbuf); gather prefetched 1 step ahead.
// ---------------------------------------------------------------------------
__global__ __launch_bounds__(512, 2) void lstm_kernel(
    const u16* __restrict__ Xih,   // [N,512] bf16
    const int* __restrict__ nbr,   // [N,16]
    const float* __restrict__ Whh, // [512,128] f32
    u16* __restrict__ Hout,        // [N,128] bf16
    int N)
{
    __shared__ u16 hbuf[2][64][136];
    __shared__ int nbrs[16][72];   // [step][node], padded
    const int tid  = threadIdx.x;
    const int lane = tid & 63;
    const int w    = tid >> 6;           // wave 0..7
    const int l15  = lane & 15;
    const int quad = lane >> 4;
    const int base = blockIdx.x * 64;

    // Whh A-fragments (register-resident): rows = output dims 128g+16w+l15
    short8 whA[4][4];
#pragma unroll
    for (int g = 0; g < 4; ++g) {
        int row = 128 * g + 16 * w + l15;
        const float* wp = Whh + (size_t)row * 128 + quad * 8;
#pragma unroll
        for (int kb = 0; kb < 4; ++kb) whA[g][kb] = ldfrag(wp + kb * 32);
    }
    // identity A-frag: A[m][k] = (k == m + 16*(w&1))
    short8 I;
    {
        int off = (w & 1) ? 16 : 0;
#pragma unroll
        for (int j = 0; j < 8; ++j) {
            int k = quad * 8 + j;
            I[j] = (short)((k == l15 + off) ? 0x3F80 : 0);
        }
    }
    // zero both h buffers; stage neighbor indices (coalesced global reads)
    u32* hz = (u32*)&hbuf[0][0][0];
    for (int i = tid; i < 2 * 64 * 136 / 2; i += 512) hz[i] = 0u;
    for (int i = tid; i < 64 * 16; i += 512) {
        int node = base + (i >> 4);
        if (node >= N) node = N - 1;
        nbrs[i & 15][i >> 4] = nbr[(size_t)node * 16 + (i & 15)];
    }
    __syncthreads();

    const int xcol0 = 32 * (w >> 1);   // 32-col window containing this wave's slice
    // prefetch step 0 gather: B-frag lane n=l15 holds 8 cols of node's Xih row
    short8 xf[4][4];                   // [nb][g]
#pragma unroll
    for (int nb = 0; nb < 4; ++nb) {
        int node = nbrs[0][l15 + 16 * nb];
        const u16* xp = Xih + (size_t)node * 512 + xcol0 + quad * 8;
#pragma unroll
        for (int g = 0; g < 4; ++g) xf[nb][g] = *(const short8*)(xp + 128 * g);
    }

    const float4_t z4 = {0.f, 0.f, 0.f, 0.f};
    float4_t c[4];
#pragma unroll
    for (int nb = 0; nb < 4; ++nb) c[nb] = z4;
    float4_t hlast[4];

    for (int t = 0; t < 16; ++t) {
        const int p = t & 1;
#pragma unroll
        for (int nb = 0; nb < 4; ++nb) {
            // h(t-1) B-frags from LDS
            const u16* hp = &hbuf[p][l15 + 16 * nb][quad * 8];
            short8 hb[4];
#pragma unroll
            for (int kb = 0; kb < 4; ++kb) hb[kb] = *(const short8*)(hp + kb * 32);
            // inject gathered X_ih via identity-MFMA (consumes xf[nb])
            float4_t z[4];
#pragma unroll
            for (int g = 0; g < 4; ++g) z[g] = mfma16(I, xf[nb][g], z4);
            // prefetch next step's gather into xf[nb] (WAR-safe: MFMA issued)
            if (t < 15) {
                int node = nbrs[t + 1][l15 + 16 * nb];
                const u16* xp = Xih + (size_t)node * 512 + xcol0 + quad * 8;
#pragma unroll
                for (int g = 0; g < 4; ++g) xf[nb][g] = *(const short8*)(xp + 128 * g);
            }
            // recurrent GEMM
#pragma unroll
            for (int g = 0; g < 4; ++g)
#pragma unroll
                for (int kb = 0; kb < 4; ++kb)
                    z[g] = mfma16(whA[g][kb], hb[kb], z[g]);
            // gates (lane holds dims 16w+quad*4+r of node l15+16nb)
            float4_t hv;
#pragma unroll
            for (int r = 0; r < 4; ++r) {
                float i_ = sigm(z[0][r]);
                float f_ = sigm(z[1][r]);
                float g_ = tanh_(z[2][r]);
                float o_ = sigm(z[3][r]);
                float cc = f_ * c[nb][r] + i_ * g_;
                c[nb][r] = cc;
                hv[r] = o_ * tanh_(cc);
            }
            hlast[nb] = hv;
            // packed h write: 4 contiguous bf16 dims -> one ds_write_b64
            u64 pkd = ((u64)pk2bf(hv[3], hv[2]) << 32) | pk2bf(hv[1], hv[0]);
            *(u64*)&hbuf[1 - p][l15 + 16 * nb][16 * w + quad * 4] = pkd;
        }
        __syncthreads();
    }
#pragma unroll
    for (int nb = 0; nb < 4; ++nb) {
        int row = base + l15 + 16 * nb;
        if (row < N) {
            u64 pkd = ((u64)pk2bf(hlast[nb][3], hlast[nb][2]) << 32)
                      | pk2bf(hlast[nb][1], hlast[nb][0]);
            *(u64*)(Hout + (size_t)row * 128 + 16 * w + quad * 4) = pkd;
        }
    }
}

// ---------------------------------------------------------------------------
__global__ void zero_stats(float* s) { s[threadIdx.x] = 0.f; }   // 256 thr

__global__ void bn_prep(float* stats, const float* __restrict__ gamma,
                        const float* __restrict__ beta, float invN)
{
    int cidx = threadIdx.x;   // 0..127
    float s = stats[cidx], sq = stats[128 + cidx];
    float mu = s * invN;
    float var = sq * invN - mu * mu;
    float sc = gamma[cidx] * rsqrtf(var + 1e-5f);
    stats[256 + cidx] = sc;
    stats[384 + cidx] = beta[cidx] - mu * sc;
}

template<typename OT>
__global__ __launch_bounds__(256) void bn_apply(
    const float* __restrict__ X, const float* __restrict__ stats,
    OT* __restrict__ Y, int M, int relu)
{
    int gid = blockIdx.x * 256 + threadIdx.x;
    int row = gid >> 4;
    int cs  = (gid & 15) * 8;
    if (row >= M) return;
    float4_t a = *(const float4_t*)(X + (size_t)row * 128 + cs);
    float4_t b = *(const float4_t*)(X + (size_t)row * 128 + cs + 4);
    float v[8];
#pragma unroll
    for (int j = 0; j < 8; ++j) {
        float x = (j < 4) ? a[j] : b[j - 4];
        float t = x * stats[256 + cs + j] + stats[384 + cs + j];
        v[j] = relu ? fmaxf(t, 0.f) : t;
    }
    if constexpr (sizeof(OT) == 2) {
        short8 ov;
#pragma unroll
        for (int j = 0; j < 8; ++j) ov[j] = (short)f2bf(v[j]);
        *(short8*)((u16*)Y + (size_t)row * 128 + cs) = ov;
    } else {
        float4_t o1, o2;
#pragma unroll
        for (int j = 0; j < 4; ++j) { o1[j] = v[j]; o2[j] = v[4 + j]; }
        *(float4_t*)((float*)Y + (size_t)row * 128 + cs) = o1;
        *(float4_t*)((float*)Y + (size_t)row * 128 + cs + 4) = o2;
    }
}

// ---------------------------------------------------------------------------
extern "C" void kernel_launch(void* const* d_in, const int* in_sizes, int n_in,
                              void* d_out, int out_size, void* d_ws, size_t ws_size,
                              hipStream_t stream)
{
    const float* in_feat = (const float*)d_in[0];
    const int*   nbr     = (const int*)d_in[1];
    const float* Wih1 = (const float*)d_in[2];
    const float* Whh1 = (const float*)d_in[3];
    const float* bih1 = (const float*)d_in[4];
    const float* bhh1 = (const float*)d_in[5];
    const float* Wself1  = (const float*)d_in[6];
    const float* bself1  = (const float*)d_in[7];
    const float* Wneigh1 = (const float*)d_in[8];
    const float* gamma1  = (const float*)d_in[9];
    const float* beta1   = (const float*)d_in[10];
    const float* Wih2 = (const float*)d_in[11];
    const float* Whh2 = (const float*)d_in[12];
    const float* bih2 = (const float*)d_in[13];
    const float* bhh2 = (const float*)d_in[14];
    const float* Wself2  = (const float*)d_in[15];
    const float* bself2  = (const float*)d_in[16];
    const float* Wneigh2 = (const float*)d_in[17];
    const float* gamma2  = (const float*)d_in[18];
    const float* beta2   = (const float*)d_in[19];

    const int N = in_sizes[0] / 128;

    char* ws = (char*)d_ws;
    u16*   Xih   = (u16*)ws;                       // [N,512] bf16 (aliases Pbuf)
    float* Pbuf  = (float*)ws;                     // [N,128] f32
    u16*   hn    = (u16*)(ws + (size_t)N * 1024);  // [N,128] bf16
    float* stats = (float*)(ws + (size_t)N * 1024 + (size_t)N * 256);
    u16*   hcur  = (u16*)d_out;                    // bf16 scratch inside d_out

    const int nblk = (N + 63) / 64;
    const float invN = 1.0f / (float)N;
    const int bnblk = (N * 16 + 255) / 256;

    // ---------------- layer 1 ----------------
    zero_stats<<<dim3(1), dim3(256), 0, stream>>>(stats);
    gemm_ih<float><<<dim3(nblk, 4), dim3(256), 0, stream>>>(in_feat, Wih1, bih1, bhh1, Xih, N);
    lstm_kernel<<<dim3(nblk), dim3(512), 0, stream>>>(Xih, nbr, Whh1, hn, N);
    gemm_out<float><<<dim3(nblk, 1), dim3(256), 0, stream>>>(hn, Wneigh1, in_feat, Wself1,
                                                             bself1, Pbuf, stats, N);
    bn_prep<<<dim3(1), dim3(128), 0, stream>>>(stats, gamma1, beta1, invN);
    bn_apply<u16><<<dim3(bnblk), dim3(256), 0, stream>>>(Pbuf, stats, hcur, N, 1);

    // ---------------- layer 2 ----------------
    zero_stats<<<dim3(1), dim3(256), 0, stream>>>(stats);
    gemm_ih<u16><<<dim3(nblk, 4), dim3(256), 0, stream>>>(hcur, Wih2, bih2, bhh2, Xih, N);
    lstm_kernel<<<dim3(nblk), dim3(512), 0, stream>>>(Xih, nbr, Whh2, hn, N);
    gemm_out<u16><<<dim3(nblk, 1), dim3(256), 0, stream>>>(hn, Wneigh2, hcur, Wself2,
                                                           bself2, Pbuf, stats, N);
    bn_prep<<<dim3(1), dim3(128), 0, stream>>>(stats, gamma2, beta2, invN);
    bn_apply<float><<<dim3(bnblk), dim3(256), 0, stream>>>(Pbuf, stats, (float*)d_out, N, 0);
}